// Round 7
// baseline (372.106 us; speedup 1.0000x reference)
//
#include <hip/hip_runtime.h>

#define N_NODES 50000
#define N_EDGES 600000

typedef short bf16x8 __attribute__((ext_vector_type(8)));
typedef float f32x4  __attribute__((ext_vector_type(4)));
typedef unsigned short u16x8 __attribute__((ext_vector_type(8)));
typedef unsigned short u16x4 __attribute__((ext_vector_type(4)));

// ---------------- bf16 helpers (RNE) ----------------
__device__ inline ushort rne_bf16(float a) {
    union { float f; unsigned u; } v; v.f = a;
    return (ushort)((v.u + 0x7FFFu + ((v.u >> 16) & 1u)) >> 16);
}
__device__ inline float bf16_to_f32(ushort h) {
    return __uint_as_float((unsigned)h << 16);
}
__device__ inline void split_bf16(float a, ushort& hi, ushort& lo) {
    hi = rne_bf16(a);
    float hv = bf16_to_f32(hi);
    lo = rne_bf16(a - hv);
}

// ---------------- CSR build ----------------

__global__ void count_deg_kernel(const int* __restrict__ dst, int* __restrict__ deg, int ne) {
    int e = blockIdx.x * blockDim.x + threadIdx.x;
    if (e < ne) atomicAdd(&deg[dst[e]], 1);
}

__global__ __launch_bounds__(256) void block_sums_kernel(const int* __restrict__ deg,
                                                         int* __restrict__ bsum, int n) {
    __shared__ int s[256];
    int t = threadIdx.x;
    int i = blockIdx.x * 256 + t;
    s[t] = (i < n) ? deg[i] : 0;
    __syncthreads();
    #pragma unroll
    for (int d = 128; d > 0; d >>= 1) {
        if (t < d) s[t] += s[t + d];
        __syncthreads();
    }
    if (t == 0) bsum[blockIdx.x] = s[0];
}

__global__ __launch_bounds__(256) void scan_bsums_kernel(const int* __restrict__ bsum,
                                                         int* __restrict__ base, int nb,
                                                         int* __restrict__ off, int n) {
    __shared__ int s[256];
    int t = threadIdx.x;
    int v = (t < nb) ? bsum[t] : 0;
    s[t] = v;
    __syncthreads();
    #pragma unroll
    for (int d = 1; d < 256; d <<= 1) {
        int x = (t >= d) ? s[t - d] : 0;
        __syncthreads();
        s[t] += x;
        __syncthreads();
    }
    if (t < nb) base[t] = s[t] - v;
    if (t == 255) off[n] = s[255];
}

__global__ __launch_bounds__(256) void scatter_offsets_kernel(const int* __restrict__ deg,
                                                              const int* __restrict__ base,
                                                              int* __restrict__ off,
                                                              int* __restrict__ cur, int n) {
    __shared__ int s[256];
    int t = threadIdx.x;
    int i = blockIdx.x * 256 + t;
    int v = (i < n) ? deg[i] : 0;
    s[t] = v;
    __syncthreads();
    #pragma unroll
    for (int d = 1; d < 256; d <<= 1) {
        int x = (t >= d) ? s[t - d] : 0;
        __syncthreads();
        s[t] += x;
        __syncthreads();
    }
    if (i < n) {
        int excl = s[t] - v + base[blockIdx.x];
        off[i] = excl;
        cur[i] = excl;
    }
}

__global__ void fill_csr_kernel(const int* __restrict__ src, const int* __restrict__ dst,
                                int* __restrict__ cur, int* __restrict__ ssrc, int ne) {
    int e = blockIdx.x * blockDim.x + threadIdx.x;
    if (e < ne) {
        int p = atomicAdd(&cur[dst[e]], 1);
        ssrc[p] = src[e];
    }
}

// ---------------- weight pre-convert ----------------
__global__ void convert_w_kernel(const float* __restrict__ Ws, const float* __restrict__ Wn,
                                 int dout, ushort* __restrict__ Bth, ushort* __restrict__ Btl) {
    int n = blockIdx.x;
    int k = threadIdx.x;
    float w = (n < dout) ? Ws[(long)k * dout + n] : Wn[(long)k * dout + (n - dout)];
    ushort hi, lo;
    split_bf16(w, hi, lo);
    Bth[n * 128 + k] = hi;
    Btl[n * 128 + k] = lo;
}

// ---------------- feat pre-split: fp32[N*128] -> hi/lo bf16 ----------------
// 800000 threads x 8 elems. Streaming, coalesced.
__global__ __launch_bounds__(256) void convert_feat_kernel(const float* __restrict__ A,
                                                           ushort* __restrict__ Ah,
                                                           ushort* __restrict__ Al) {
    long g = ((long)blockIdx.x * 256 + threadIdx.x) * 8;
    float4 a0 = *(const float4*)(A + g);
    float4 a1 = *(const float4*)(A + g + 4);
    float f[8] = {a0.x, a0.y, a0.z, a0.w, a1.x, a1.y, a1.z, a1.w};
    u16x8 h, l;
    #pragma unroll
    for (int i = 0; i < 8; ++i) {
        ushort hh, ll;
        split_bf16(f[i], hh, ll);
        h[i] = hh; l[i] = ll;
    }
    *(u16x8*)(Ah + g) = h;
    *(u16x8*)(Al + g) = l;
}

// ---------------- split-bf16 MFMA dual GEMM — pre-split A, no LDS, no barriers ----
// A given as Ah/Al bf16 [Mpad][128] (fragment-ready). B from Bt tables [NCOL][128].
// MFMA pass-major (hh all accs, hl all accs, lh all accs) for dependency slack.

#define KDIM 128

// Layers 0/1: NCOL=256. Block 256 thr = 4 waves; wave = 32 rows x 64 cols.
// Grid x = ceil(M/32). Rows beyond M read garbage (padded buffer), never stored.
__global__ __launch_bounds__(256) void gemm_mfma_wide(
    const ushort* __restrict__ Ah, const ushort* __restrict__ Al,
    const ushort* __restrict__ Bth, const ushort* __restrict__ Btl,
    const float* __restrict__ bias,
    float* __restrict__ S, ushort* __restrict__ T, int M)
{
    const int tid = threadIdx.x;
    const int brow = blockIdx.x * 32;
    const int wave = tid >> 6;
    const int lane = tid & 63;
    const int lane16 = lane & 15;
    const int quad = lane >> 4;
    const int colbase = wave * 64;

    f32x4 acc[2][4] = {};   // [row tile][col tile]

    #pragma unroll
    for (int c = 0; c < 4; ++c) {
        const int k0 = c * 32;
        bf16x8 ah[2], al[2], bh[4], bl[4];
        #pragma unroll
        for (int rt = 0; rt < 2; ++rt) {
            long aoff = (long)(brow + 16 * rt + lane16) * KDIM + k0 + quad * 8;
            ah[rt] = *(const bf16x8*)(Ah + aoff);
            al[rt] = *(const bf16x8*)(Al + aoff);
        }
        #pragma unroll
        for (int ct = 0; ct < 4; ++ct) {
            long boff = (long)(colbase + 16 * ct + lane16) * KDIM + k0 + quad * 8;
            bh[ct] = *(const bf16x8*)(Bth + boff);
            bl[ct] = *(const bf16x8*)(Btl + boff);
        }
        // pass 1: a_hi * b_hi
        #pragma unroll
        for (int ct = 0; ct < 4; ++ct)
            #pragma unroll
            for (int rt = 0; rt < 2; ++rt)
                acc[rt][ct] = __builtin_amdgcn_mfma_f32_16x16x32_bf16(ah[rt], bh[ct], acc[rt][ct], 0, 0, 0);
        // pass 2: a_hi * b_lo
        #pragma unroll
        for (int ct = 0; ct < 4; ++ct)
            #pragma unroll
            for (int rt = 0; rt < 2; ++rt)
                acc[rt][ct] = __builtin_amdgcn_mfma_f32_16x16x32_bf16(ah[rt], bl[ct], acc[rt][ct], 0, 0, 0);
        // pass 3: a_lo * b_hi
        #pragma unroll
        for (int ct = 0; ct < 4; ++ct)
            #pragma unroll
            for (int rt = 0; rt < 2; ++rt)
                acc[rt][ct] = __builtin_amdgcn_mfma_f32_16x16x32_bf16(al[rt], bh[ct], acc[rt][ct], 0, 0, 0);
    }

    #pragma unroll
    for (int ct = 0; ct < 4; ++ct) {
        int col = colbase + 16 * ct + lane16;
        bool toS = col < 128;
        float bv = toS ? bias[col] : 0.f;
        int tcol = toS ? col : col - 128;
        #pragma unroll
        for (int rt = 0; rt < 2; ++rt) {
            #pragma unroll
            for (int i = 0; i < 4; ++i) {
                int row = brow + 16 * rt + quad * 4 + i;
                if (row < M) {
                    if (toS) S[(long)row * 128 + tcol] = acc[rt][ct][i] + bv;
                    else     T[(long)row * 128 + tcol] = rne_bf16(acc[rt][ct][i]);
                }
            }
        }
    }
}

// Layer 2: NCOL=80. Block 256 = 4 waves; wave = 16 rows x 80 cols. Grid x = ceil(M/64).
__global__ __launch_bounds__(256) void gemm_mfma_narrow(
    const ushort* __restrict__ Ah, const ushort* __restrict__ Al,
    const ushort* __restrict__ Bth, const ushort* __restrict__ Btl,
    const float* __restrict__ bias,
    float* __restrict__ S, ushort* __restrict__ T, int M)
{
    const int tid = threadIdx.x;
    const int wave = tid >> 6;
    const int brow = blockIdx.x * 64 + wave * 16;
    const int lane = tid & 63;
    const int lane16 = lane & 15;
    const int quad = lane >> 4;

    f32x4 acc[5] = {};

    #pragma unroll
    for (int c = 0; c < 4; ++c) {
        const int k0 = c * 32;
        long aoff = (long)(brow + lane16) * KDIM + k0 + quad * 8;
        bf16x8 ah = *(const bf16x8*)(Ah + aoff);
        bf16x8 al = *(const bf16x8*)(Al + aoff);
        bf16x8 bh[5], bl[5];
        #pragma unroll
        for (int ct = 0; ct < 5; ++ct) {
            long boff = (long)(16 * ct + lane16) * KDIM + k0 + quad * 8;
            bh[ct] = *(const bf16x8*)(Bth + boff);
            bl[ct] = *(const bf16x8*)(Btl + boff);
        }
        #pragma unroll
        for (int ct = 0; ct < 5; ++ct)
            acc[ct] = __builtin_amdgcn_mfma_f32_16x16x32_bf16(ah, bh[ct], acc[ct], 0, 0, 0);
        #pragma unroll
        for (int ct = 0; ct < 5; ++ct)
            acc[ct] = __builtin_amdgcn_mfma_f32_16x16x32_bf16(ah, bl[ct], acc[ct], 0, 0, 0);
        #pragma unroll
        for (int ct = 0; ct < 5; ++ct)
            acc[ct] = __builtin_amdgcn_mfma_f32_16x16x32_bf16(al, bh[ct], acc[ct], 0, 0, 0);
    }

    #pragma unroll
    for (int ct = 0; ct < 5; ++ct) {
        int col = 16 * ct + lane16;
        bool toS = col < 40;
        float bv = toS ? bias[col] : 0.f;
        int tcol = toS ? col : col - 40;
        #pragma unroll
        for (int i = 0; i < 4; ++i) {
            int row = brow + quad * 4 + i;
            if (row < M) {
                if (toS) S[(long)row * 40 + tcol] = acc[ct][i] + bv;
                else     T[(long)row * 40 + tcol] = rne_bf16(acc[ct][i]);
            }
        }
    }
}

// ---------------- aggregation, wave-per-node, bf16 gather ----------------
// Layers 0/1: out = relu(S + mean_gather(T)), written pre-split as hi/lo bf16
// (next GEMM's A). Layer 2 variant writes fp32 d_out.

__global__ __launch_bounds__(256) void agg128_split_kernel(
    const float* __restrict__ S, const ushort* __restrict__ T,
    const int* __restrict__ off, const int* __restrict__ ssrc,
    ushort* __restrict__ Oh, ushort* __restrict__ Ol, int nnodes)
{
    const int node = (blockIdx.x * 256 + threadIdx.x) >> 6;
    if (node >= nnodes) return;
    const int lane = threadIdx.x & 63;
    const int slot = lane >> 4;          // 0..3
    const int col8 = (lane & 15) * 8;    // 8 features per lane

    const int a = off[node];
    const int b = off[node + 1];

    f32x4 acc0a = {0,0,0,0}, acc0b = {0,0,0,0};
    f32x4 acc1a = {0,0,0,0}, acc1b = {0,0,0,0};

    int i = a;
    for (; i + 8 <= b; i += 8) {
        int s0 = ssrc[i + slot];
        int s1 = ssrc[i + 4 + slot];
        u16x8 v0 = *(const u16x8*)(T + (long)s0 * 128 + col8);
        u16x8 v1 = *(const u16x8*)(T + (long)s1 * 128 + col8);
        #pragma unroll
        for (int j = 0; j < 4; ++j) {
            acc0a[j] += bf16_to_f32(v0[j]);
            acc0b[j] += bf16_to_f32(v0[4 + j]);
            acc1a[j] += bf16_to_f32(v1[j]);
            acc1b[j] += bf16_to_f32(v1[4 + j]);
        }
    }
    for (; i < b; i += 4) {
        int e = i + slot;
        if (e < b) {
            int s = ssrc[e];
            u16x8 v = *(const u16x8*)(T + (long)s * 128 + col8);
            #pragma unroll
            for (int j = 0; j < 4; ++j) {
                acc0a[j] += bf16_to_f32(v[j]);
                acc0b[j] += bf16_to_f32(v[4 + j]);
            }
        }
    }
    f32x4 accA = acc0a + acc1a;
    f32x4 accB = acc0b + acc1b;

    #pragma unroll
    for (int m = 16; m <= 32; m <<= 1) {
        #pragma unroll
        for (int j = 0; j < 4; ++j) {
            accA[j] += __shfl_xor((float)accA[j], m);
            accB[j] += __shfl_xor((float)accB[j], m);
        }
    }

    if (slot == 0) {
        int deg = b - a;
        float scale = (deg > 0) ? (1.0f / (float)deg) : 0.f;
        f32x4 sA = *(const f32x4*)(S + (long)node * 128 + col8);
        f32x4 sB = *(const f32x4*)(S + (long)node * 128 + col8 + 4);
        float r[8];
        #pragma unroll
        for (int j = 0; j < 4; ++j) {
            r[j]     = fmaxf(sA[j] + accA[j] * scale, 0.f);
            r[4 + j] = fmaxf(sB[j] + accB[j] * scale, 0.f);
        }
        u16x8 h, l;
        #pragma unroll
        for (int j = 0; j < 8; ++j) {
            ushort hh, ll;
            split_bf16(r[j], hh, ll);
            h[j] = hh; l[j] = ll;
        }
        *(u16x8*)(Oh + (long)node * 128 + col8) = h;
        *(u16x8*)(Ol + (long)node * 128 + col8) = l;
    }
}

__global__ __launch_bounds__(256) void agg40_kernel(
    const float* __restrict__ S, const ushort* __restrict__ T,
    const int* __restrict__ off, const int* __restrict__ ssrc,
    float* __restrict__ out, int nnodes)
{
    const int node = (blockIdx.x * 256 + threadIdx.x) >> 6;
    if (node >= nnodes) return;
    const int lane = threadIdx.x & 63;
    const bool active = lane < 60;
    const int slot = active ? (lane / 10) : 5;   // 0..5
    const int fi = lane % 10;
    const int fo = fi * 4;

    const int a = off[node];
    const int b = off[node + 1];

    f32x4 acc0 = {0,0,0,0}, acc1 = {0,0,0,0};

    int i = a;
    for (; i + 12 <= b; i += 12) {
        int s0 = ssrc[i + slot];
        int s1 = ssrc[i + 6 + slot];
        u16x4 v0 = *(const u16x4*)(T + (long)s0 * 40 + fo);
        u16x4 v1 = *(const u16x4*)(T + (long)s1 * 40 + fo);
        if (active) {
            #pragma unroll
            for (int j = 0; j < 4; ++j) {
                acc0[j] += bf16_to_f32(v0[j]);
                acc1[j] += bf16_to_f32(v1[j]);
            }
        }
    }
    for (; i < b; i += 6) {
        int e = i + slot;
        if (active && e < b) {
            int s = ssrc[e];
            u16x4 v = *(const u16x4*)(T + (long)s * 40 + fo);
            #pragma unroll
            for (int j = 0; j < 4; ++j) acc0[j] += bf16_to_f32(v[j]);
        }
    }
    f32x4 acc = acc0 + acc1;

    f32x4 tot = acc;
    #pragma unroll
    for (int d = 10; d <= 50; d += 10) {
        int srcl = fi + d;
        #pragma unroll
        for (int j = 0; j < 4; ++j) tot[j] += __shfl((float)acc[j], srcl);
    }

    if (lane < 10) {
        int deg = b - a;
        float scale = (deg > 0) ? (1.0f / (float)deg) : 0.f;
        f32x4 s4 = *(const f32x4*)(S + (long)node * 40 + fo);
        f32x4 r = s4 + tot * scale;
        *(f32x4*)(out + (long)node * 40 + fo) = r;
    }
}

// ---------------- launch ----------------

extern "C" void kernel_launch(void* const* d_in, const int* in_sizes, int n_in,
                              void* d_out, int out_size, void* d_ws, size_t ws_size,
                              hipStream_t stream) {
    const float* feat = (const float*)d_in[0];
    const int*   src  = (const int*)d_in[1];
    const int*   dst  = (const int*)d_in[2];
    const float* ws0  = (const float*)d_in[3];
    const float* wn0  = (const float*)d_in[4];
    const float* b0   = (const float*)d_in[5];
    const float* ws1  = (const float*)d_in[6];
    const float* wn1  = (const float*)d_in[7];
    const float* b1   = (const float*)d_in[8];
    const float* ws2  = (const float*)d_in[9];
    const float* wn2  = (const float*)d_in[10];
    const float* b2   = (const float*)d_in[11];

    const int N = N_NODES;
    const int NE = N_EDGES;
    const int NB = (N + 255) / 256;  // 196

    char* ws = (char*)d_ws;
    int*    offsets = (int*)(ws + 0);
    int*    cursor  = (int*)(ws + 200704);
    int*    degi    = (int*)(ws + 401408);
    int*    bsum    = (int*)(ws + 601600);
    int*    bbase   = (int*)(ws + 602432);
    int*    ssrc    = (int*)(ws + 603648);      // ends 3,003,648
    ushort* Bth0 = (ushort*)(ws + 200704);      // overlap cursor/degi; written after CSR build
    ushort* Btl0 = (ushort*)(ws + 266240);
    ushort* Bth1 = (ushort*)(ws + 331776);
    ushort* Btl1 = (ushort*)(ws + 397312);
    ushort* Bth2 = (ushort*)(ws + 462848);
    ushort* Btl2 = (ushort*)(ws + 483328);      // ends 503,808
    // activation hi/lo (A for GEMMs), padded +64 rows so OOB tile reads stay in-bounds
    ushort* fh   = (ushort*)(ws + 3010560);     // 50064*128*2 = 12,816,384
    ushort* fl   = (ushort*)(ws + 15827200);    // same size, ends ~28.6 MB
    float*  sbuf = (float*)(ws + 28643840);     // 25.6 MB fp32
    ushort* tbuf = (ushort*)(ws + 54244096);    // 12.8 MB bf16

    // ---- CSR build ----
    hipMemsetAsync(degi, 0, (size_t)N * sizeof(int), stream);
    count_deg_kernel<<<(NE + 255) / 256, 256, 0, stream>>>(dst, degi, NE);
    block_sums_kernel<<<NB, 256, 0, stream>>>(degi, bsum, N);
    scan_bsums_kernel<<<1, 256, 0, stream>>>(bsum, bbase, NB, offsets, N);
    scatter_offsets_kernel<<<NB, 256, 0, stream>>>(degi, bbase, offsets, cursor, N);
    fill_csr_kernel<<<(NE + 255) / 256, 256, 0, stream>>>(src, dst, cursor, ssrc, NE);

    // ---- weight + feat pre-convert ----
    convert_w_kernel<<<256, 128, 0, stream>>>(ws0, wn0, 128, Bth0, Btl0);
    convert_w_kernel<<<256, 128, 0, stream>>>(ws1, wn1, 128, Bth1, Btl1);
    convert_w_kernel<<<80, 128, 0, stream>>>(ws2, wn2, 40, Bth2, Btl2);
    convert_feat_kernel<<<(N * 128 / 8 + 255) / 256, 256, 0, stream>>>(feat, fh, fl);

    const int gw = (N + 31) / 32;        // 1563 wide-GEMM blocks (32 rows each)
    const int gn = (N + 63) / 64;        // 782 narrow-GEMM blocks
    const int ga = (N + 3) / 4;          // 12500 agg blocks (4 waves/block)

    // ---- layer 0 ----
    gemm_mfma_wide<<<gw, 256, 0, stream>>>(fh, fl, Bth0, Btl0, b0, sbuf, tbuf, N);
    agg128_split_kernel<<<ga, 256, 0, stream>>>(sbuf, tbuf, offsets, ssrc, fh, fl, N);

    // ---- layer 1 ----
    gemm_mfma_wide<<<gw, 256, 0, stream>>>(fh, fl, Bth1, Btl1, b1, sbuf, tbuf, N);
    agg128_split_kernel<<<ga, 256, 0, stream>>>(sbuf, tbuf, offsets, ssrc, fh, fl, N);

    // ---- layer 2 ----
    gemm_mfma_narrow<<<gn, 256, 0, stream>>>(fh, fl, Bth2, Btl2, b2, sbuf, tbuf, N);
    agg40_kernel<<<ga, 256, 0, stream>>>(sbuf, tbuf, offsets, ssrc, (float*)d_out, N);
}

// Round 8
// 338.848 us; speedup vs baseline: 1.0981x; 1.0981x over previous
//
#include <hip/hip_runtime.h>

#define N_NODES 50000
#define N_EDGES 600000

typedef short bf16x8 __attribute__((ext_vector_type(8)));
typedef float f32x4  __attribute__((ext_vector_type(4)));
typedef unsigned short u16x8 __attribute__((ext_vector_type(8)));
typedef unsigned short u16x4 __attribute__((ext_vector_type(4)));

typedef __attribute__((address_space(1))) unsigned int u32_g;
typedef __attribute__((address_space(3))) unsigned int u32_l;

__device__ inline void g2lds16(const void* g, void* l) {
    __builtin_amdgcn_global_load_lds((const u32_g*)g, (u32_l*)l, 16, 0, 0);
}

// ---------------- bf16 helpers (RNE) ----------------
__device__ inline ushort rne_bf16(float a) {
    union { float f; unsigned u; } v; v.f = a;
    return (ushort)((v.u + 0x7FFFu + ((v.u >> 16) & 1u)) >> 16);
}
__device__ inline float bf16_to_f32(ushort h) {
    return __uint_as_float((unsigned)h << 16);
}
__device__ inline void split_bf16(float a, ushort& hi, ushort& lo) {
    hi = rne_bf16(a);
    float hv = bf16_to_f32(hi);
    lo = rne_bf16(a - hv);
}

// ---------------- CSR build ----------------

__global__ void count_deg_kernel(const int* __restrict__ dst, int* __restrict__ deg, int ne) {
    int e = blockIdx.x * blockDim.x + threadIdx.x;
    if (e < ne) atomicAdd(&deg[dst[e]], 1);
}

__global__ __launch_bounds__(256) void block_sums_kernel(const int* __restrict__ deg,
                                                         int* __restrict__ bsum, int n) {
    __shared__ int s[256];
    int t = threadIdx.x;
    int i = blockIdx.x * 256 + t;
    s[t] = (i < n) ? deg[i] : 0;
    __syncthreads();
    #pragma unroll
    for (int d = 128; d > 0; d >>= 1) {
        if (t < d) s[t] += s[t + d];
        __syncthreads();
    }
    if (t == 0) bsum[blockIdx.x] = s[0];
}

__global__ __launch_bounds__(256) void scan_bsums_kernel(const int* __restrict__ bsum,
                                                         int* __restrict__ base, int nb,
                                                         int* __restrict__ off, int n) {
    __shared__ int s[256];
    int t = threadIdx.x;
    int v = (t < nb) ? bsum[t] : 0;
    s[t] = v;
    __syncthreads();
    #pragma unroll
    for (int d = 1; d < 256; d <<= 1) {
        int x = (t >= d) ? s[t - d] : 0;
        __syncthreads();
        s[t] += x;
        __syncthreads();
    }
    if (t < nb) base[t] = s[t] - v;
    if (t == 255) off[n] = s[255];
}

__global__ __launch_bounds__(256) void scatter_offsets_kernel(const int* __restrict__ deg,
                                                              const int* __restrict__ base,
                                                              int* __restrict__ off,
                                                              int* __restrict__ cur, int n) {
    __shared__ int s[256];
    int t = threadIdx.x;
    int i = blockIdx.x * 256 + t;
    int v = (i < n) ? deg[i] : 0;
    s[t] = v;
    __syncthreads();
    #pragma unroll
    for (int d = 1; d < 256; d <<= 1) {
        int x = (t >= d) ? s[t - d] : 0;
        __syncthreads();
        s[t] += x;
        __syncthreads();
    }
    if (i < n) {
        int excl = s[t] - v + base[blockIdx.x];
        off[i] = excl;
        cur[i] = excl;
    }
}

__global__ void fill_csr_kernel(const int* __restrict__ src, const int* __restrict__ dst,
                                int* __restrict__ cur, int* __restrict__ ssrc, int ne) {
    int e = blockIdx.x * blockDim.x + threadIdx.x;
    if (e < ne) {
        int p = atomicAdd(&cur[dst[e]], 1);
        ssrc[p] = src[e];
    }
}

// ---------------- weight pre-convert ----------------
__global__ void convert_w_kernel(const float* __restrict__ Ws, const float* __restrict__ Wn,
                                 int dout, ushort* __restrict__ Bth, ushort* __restrict__ Btl) {
    int n = blockIdx.x;
    int k = threadIdx.x;
    float w = (n < dout) ? Ws[(long)k * dout + n] : Wn[(long)k * dout + (n - dout)];
    ushort hi, lo;
    split_bf16(w, hi, lo);
    Bth[n * 128 + k] = hi;
    Btl[n * 128 + k] = lo;
}

// ---------------- feat pre-split: fp32[N*128] -> hi/lo bf16 ----------------
__global__ __launch_bounds__(256) void convert_feat_kernel(const float* __restrict__ A,
                                                           ushort* __restrict__ Ah,
                                                           ushort* __restrict__ Al) {
    long g = ((long)blockIdx.x * 256 + threadIdx.x) * 8;
    float4 a0 = *(const float4*)(A + g);
    float4 a1 = *(const float4*)(A + g + 4);
    float f[8] = {a0.x, a0.y, a0.z, a0.w, a1.x, a1.y, a1.z, a1.w};
    u16x8 h, l;
    #pragma unroll
    for (int i = 0; i < 8; ++i) {
        ushort hh, ll;
        split_bf16(f[i], hh, ll);
        h[i] = hh; l[i] = ll;
    }
    *(u16x8*)(Ah + g) = h;
    *(u16x8*)(Al + g) = l;
}

// ---------------- split-bf16 MFMA dual GEMM, B-resident ----------------
// Block: 512 thr = 8 waves; wave w -> cols [32w, 32w+32) of 256 (B in VGPRs, loaded once).
// Loop TILES row-tiles of 32; A-tile staged to LDS via global_load_lds with
// XOR-swizzled 16B units (ds_read_b128 then 2-way conflict = free).
// MFMA order per acc identical to previous round -> bitwise-same output.

#define KDIM 128
#define TILES 3
#define RPB   (32 * TILES)   // 96 rows per block

__global__ __launch_bounds__(512) void gemm_mfma_wide(
    const ushort* __restrict__ Ah, const ushort* __restrict__ Al,
    const ushort* __restrict__ Bth, const ushort* __restrict__ Btl,
    const float* __restrict__ bias,
    float* __restrict__ S, ushort* __restrict__ T, int M)
{
    __shared__ ushort AhL[32 * 128];  // 8KB: [row][u'] 16B units, u' = u ^ (row&15)
    __shared__ ushort AlL[32 * 128];

    const int tid = threadIdx.x;
    const int wave = tid >> 6;        // 0..7
    const int lane = tid & 63;
    const int lane16 = lane & 15;
    const int quad = lane >> 4;
    const int colbase = wave * 32;
    const int rowbase = blockIdx.x * RPB;

    // ---- B into registers, once per block ----
    bf16x8 bh[2][4], bl[2][4];
    #pragma unroll
    for (int ct = 0; ct < 2; ++ct) {
        #pragma unroll
        for (int c = 0; c < 4; ++c) {
            long boff = (long)(colbase + 16 * ct + lane16) * KDIM + c * 32 + quad * 8;
            bh[ct][c] = *(const bf16x8*)(Bth + boff);
            bl[ct][c] = *(const bf16x8*)(Btl + boff);
        }
    }

    // staging map: thread t -> LDS unit t (16B); fetches global unit su of row srow
    const int srow = tid >> 4;                     // 0..31
    const int su   = (tid & 15) ^ (srow & 15);     // XOR swizzle
    const int lds_wave_off = wave * 512;           // ushort offset of this wave's 1KB LDS slice

    for (int t = 0; t < TILES; ++t) {
        const int r0 = rowbase + t * 32;
        // stage A-tile (hi+lo) via global_load_lds, 16B/lane
        {
            const ushort* ga = Ah + ((long)(r0 + srow) * KDIM + su * 8);
            const ushort* gb = Al + ((long)(r0 + srow) * KDIM + su * 8);
            g2lds16(ga, (void*)(AhL + lds_wave_off));
            g2lds16(gb, (void*)(AlL + lds_wave_off));
        }
        __syncthreads();

        f32x4 acc[2][2] = {};
        #pragma unroll
        for (int c = 0; c < 4; ++c) {
            bf16x8 ah[2], al[2];
            #pragma unroll
            for (int rt = 0; rt < 2; ++rt) {
                int row = 16 * rt + lane16;
                int u = (4 * c + quad) ^ lane16;     // row&15 == lane16
                int offs = row * 128 + u * 8;
                ah[rt] = *(const bf16x8*)&AhL[offs];
                al[rt] = *(const bf16x8*)&AlL[offs];
            }
            #pragma unroll
            for (int ct = 0; ct < 2; ++ct)
                #pragma unroll
                for (int rt = 0; rt < 2; ++rt)
                    acc[rt][ct] = __builtin_amdgcn_mfma_f32_16x16x32_bf16(ah[rt], bh[ct][c], acc[rt][ct], 0, 0, 0);
            #pragma unroll
            for (int ct = 0; ct < 2; ++ct)
                #pragma unroll
                for (int rt = 0; rt < 2; ++rt)
                    acc[rt][ct] = __builtin_amdgcn_mfma_f32_16x16x32_bf16(ah[rt], bl[ct][c], acc[rt][ct], 0, 0, 0);
            #pragma unroll
            for (int ct = 0; ct < 2; ++ct)
                #pragma unroll
                for (int rt = 0; rt < 2; ++rt)
                    acc[rt][ct] = __builtin_amdgcn_mfma_f32_16x16x32_bf16(al[rt], bh[ct][c], acc[rt][ct], 0, 0, 0);
        }

        // epilogue for this tile
        #pragma unroll
        for (int ct = 0; ct < 2; ++ct) {
            int col = colbase + 16 * ct + lane16;
            bool toS = col < 128;
            float bv = toS ? bias[col] : 0.f;
            int tcol = toS ? col : col - 128;
            #pragma unroll
            for (int rt = 0; rt < 2; ++rt) {
                #pragma unroll
                for (int i = 0; i < 4; ++i) {
                    int row = r0 + 16 * rt + quad * 4 + i;
                    if (row < M) {
                        if (toS) S[(long)row * 128 + tcol] = acc[rt][ct][i] + bv;
                        else     T[(long)row * 128 + tcol] = rne_bf16(acc[rt][ct][i]);
                    }
                }
            }
        }
        __syncthreads();   // protect LDS before next stage
    }
}

// Layer 2: NCOL=80. Block 256 = 4 waves; wave = 16 rows x 80 cols. Grid x = ceil(M/64).
__global__ __launch_bounds__(256) void gemm_mfma_narrow(
    const ushort* __restrict__ Ah, const ushort* __restrict__ Al,
    const ushort* __restrict__ Bth, const ushort* __restrict__ Btl,
    const float* __restrict__ bias,
    float* __restrict__ S, ushort* __restrict__ T, int M)
{
    const int tid = threadIdx.x;
    const int wave = tid >> 6;
    const int brow = blockIdx.x * 64 + wave * 16;
    const int lane = tid & 63;
    const int lane16 = lane & 15;
    const int quad = lane >> 4;

    f32x4 acc[5] = {};

    #pragma unroll
    for (int c = 0; c < 4; ++c) {
        const int k0 = c * 32;
        long aoff = (long)(brow + lane16) * KDIM + k0 + quad * 8;
        bf16x8 ah = *(const bf16x8*)(Ah + aoff);
        bf16x8 al = *(const bf16x8*)(Al + aoff);
        bf16x8 bh[5], bl[5];
        #pragma unroll
        for (int ct = 0; ct < 5; ++ct) {
            long boff = (long)(16 * ct + lane16) * KDIM + k0 + quad * 8;
            bh[ct] = *(const bf16x8*)(Bth + boff);
            bl[ct] = *(const bf16x8*)(Btl + boff);
        }
        #pragma unroll
        for (int ct = 0; ct < 5; ++ct)
            acc[ct] = __builtin_amdgcn_mfma_f32_16x16x32_bf16(ah, bh[ct], acc[ct], 0, 0, 0);
        #pragma unroll
        for (int ct = 0; ct < 5; ++ct)
            acc[ct] = __builtin_amdgcn_mfma_f32_16x16x32_bf16(ah, bl[ct], acc[ct], 0, 0, 0);
        #pragma unroll
        for (int ct = 0; ct < 5; ++ct)
            acc[ct] = __builtin_amdgcn_mfma_f32_16x16x32_bf16(al, bh[ct], acc[ct], 0, 0, 0);
    }

    #pragma unroll
    for (int ct = 0; ct < 5; ++ct) {
        int col = 16 * ct + lane16;
        bool toS = col < 40;
        float bv = toS ? bias[col] : 0.f;
        int tcol = toS ? col : col - 40;
        #pragma unroll
        for (int i = 0; i < 4; ++i) {
            int row = brow + quad * 4 + i;
            if (row < M) {
                if (toS) S[(long)row * 40 + tcol] = acc[ct][i] + bv;
                else     T[(long)row * 40 + tcol] = rne_bf16(acc[ct][i]);
            }
        }
    }
}

// ---------------- aggregation, wave-per-node, bf16 gather ----------------

__global__ __launch_bounds__(256) void agg128_split_kernel(
    const float* __restrict__ S, const ushort* __restrict__ T,
    const int* __restrict__ off, const int* __restrict__ ssrc,
    ushort* __restrict__ Oh, ushort* __restrict__ Ol, int nnodes)
{
    const int node = (blockIdx.x * 256 + threadIdx.x) >> 6;
    if (node >= nnodes) return;
    const int lane = threadIdx.x & 63;
    const int slot = lane >> 4;          // 0..3
    const int col8 = (lane & 15) * 8;    // 8 features per lane

    const int a = off[node];
    const int b = off[node + 1];

    f32x4 acc0a = {0,0,0,0}, acc0b = {0,0,0,0};
    f32x4 acc1a = {0,0,0,0}, acc1b = {0,0,0,0};

    int i = a;
    for (; i + 8 <= b; i += 8) {
        int s0 = ssrc[i + slot];
        int s1 = ssrc[i + 4 + slot];
        u16x8 v0 = *(const u16x8*)(T + (long)s0 * 128 + col8);
        u16x8 v1 = *(const u16x8*)(T + (long)s1 * 128 + col8);
        #pragma unroll
        for (int j = 0; j < 4; ++j) {
            acc0a[j] += bf16_to_f32(v0[j]);
            acc0b[j] += bf16_to_f32(v0[4 + j]);
            acc1a[j] += bf16_to_f32(v1[j]);
            acc1b[j] += bf16_to_f32(v1[4 + j]);
        }
    }
    for (; i < b; i += 4) {
        int e = i + slot;
        if (e < b) {
            int s = ssrc[e];
            u16x8 v = *(const u16x8*)(T + (long)s * 128 + col8);
            #pragma unroll
            for (int j = 0; j < 4; ++j) {
                acc0a[j] += bf16_to_f32(v[j]);
                acc0b[j] += bf16_to_f32(v[4 + j]);
            }
        }
    }
    f32x4 accA = acc0a + acc1a;
    f32x4 accB = acc0b + acc1b;

    #pragma unroll
    for (int m = 16; m <= 32; m <<= 1) {
        #pragma unroll
        for (int j = 0; j < 4; ++j) {
            accA[j] += __shfl_xor((float)accA[j], m);
            accB[j] += __shfl_xor((float)accB[j], m);
        }
    }

    if (slot == 0) {
        int deg = b - a;
        float scale = (deg > 0) ? (1.0f / (float)deg) : 0.f;
        f32x4 sA = *(const f32x4*)(S + (long)node * 128 + col8);
        f32x4 sB = *(const f32x4*)(S + (long)node * 128 + col8 + 4);
        float r[8];
        #pragma unroll
        for (int j = 0; j < 4; ++j) {
            r[j]     = fmaxf(sA[j] + accA[j] * scale, 0.f);
            r[4 + j] = fmaxf(sB[j] + accB[j] * scale, 0.f);
        }
        u16x8 h, l;
        #pragma unroll
        for (int j = 0; j < 8; ++j) {
            ushort hh, ll;
            split_bf16(r[j], hh, ll);
            h[j] = hh; l[j] = ll;
        }
        *(u16x8*)(Oh + (long)node * 128 + col8) = h;
        *(u16x8*)(Ol + (long)node * 128 + col8) = l;
    }
}

__global__ __launch_bounds__(256) void agg40_kernel(
    const float* __restrict__ S, const ushort* __restrict__ T,
    const int* __restrict__ off, const int* __restrict__ ssrc,
    float* __restrict__ out, int nnodes)
{
    const int node = (blockIdx.x * 256 + threadIdx.x) >> 6;
    if (node >= nnodes) return;
    const int lane = threadIdx.x & 63;
    const bool active = lane < 60;
    const int slot = active ? (lane / 10) : 5;   // 0..5
    const int fi = lane % 10;
    const int fo = fi * 4;

    const int a = off[node];
    const int b = off[node + 1];

    f32x4 acc0 = {0,0,0,0}, acc1 = {0,0,0,0};

    int i = a;
    for (; i + 12 <= b; i += 12) {
        int s0 = ssrc[i + slot];
        int s1 = ssrc[i + 6 + slot];
        u16x4 v0 = *(const u16x4*)(T + (long)s0 * 40 + fo);
        u16x4 v1 = *(const u16x4*)(T + (long)s1 * 40 + fo);
        if (active) {
            #pragma unroll
            for (int j = 0; j < 4; ++j) {
                acc0[j] += bf16_to_f32(v0[j]);
                acc1[j] += bf16_to_f32(v1[j]);
            }
        }
    }
    for (; i < b; i += 6) {
        int e = i + slot;
        if (active && e < b) {
            int s = ssrc[e];
            u16x4 v = *(const u16x4*)(T + (long)s * 40 + fo);
            #pragma unroll
            for (int j = 0; j < 4; ++j) acc0[j] += bf16_to_f32(v[j]);
        }
    }
    f32x4 acc = acc0 + acc1;

    f32x4 tot = acc;
    #pragma unroll
    for (int d = 10; d <= 50; d += 10) {
        int srcl = fi + d;
        #pragma unroll
        for (int j = 0; j < 4; ++j) tot[j] += __shfl((float)acc[j], srcl);
    }

    if (lane < 10) {
        int deg = b - a;
        float scale = (deg > 0) ? (1.0f / (float)deg) : 0.f;
        f32x4 s4 = *(const f32x4*)(S + (long)node * 40 + fo);
        f32x4 r = s4 + tot * scale;
        *(f32x4*)(out + (long)node * 40 + fo) = r;
    }
}

// ---------------- launch ----------------

extern "C" void kernel_launch(void* const* d_in, const int* in_sizes, int n_in,
                              void* d_out, int out_size, void* d_ws, size_t ws_size,
                              hipStream_t stream) {
    const float* feat = (const float*)d_in[0];
    const int*   src  = (const int*)d_in[1];
    const int*   dst  = (const int*)d_in[2];
    const float* ws0  = (const float*)d_in[3];
    const float* wn0  = (const float*)d_in[4];
    const float* b0   = (const float*)d_in[5];
    const float* ws1  = (const float*)d_in[6];
    const float* wn1  = (const float*)d_in[7];
    const float* b1   = (const float*)d_in[8];
    const float* ws2  = (const float*)d_in[9];
    const float* wn2  = (const float*)d_in[10];
    const float* b2   = (const float*)d_in[11];

    const int N = N_NODES;
    const int NE = N_EDGES;
    const int NB = (N + 255) / 256;  // 196

    char* ws = (char*)d_ws;
    int*    offsets = (int*)(ws + 0);
    int*    cursor  = (int*)(ws + 200704);
    int*    degi    = (int*)(ws + 401408);
    int*    bsum    = (int*)(ws + 601600);
    int*    bbase   = (int*)(ws + 602432);
    int*    ssrc    = (int*)(ws + 603648);      // ends 3,003,648
    ushort* Bth0 = (ushort*)(ws + 200704);      // overlap cursor/degi; written after CSR build
    ushort* Btl0 = (ushort*)(ws + 266240);
    ushort* Bth1 = (ushort*)(ws + 331776);
    ushort* Btl1 = (ushort*)(ws + 397312);
    ushort* Bth2 = (ushort*)(ws + 462848);
    ushort* Btl2 = (ushort*)(ws + 483328);      // ends 503,808
    // activation hi/lo (A for GEMMs), padded +64 rows so tail tile reads stay in-bounds
    ushort* fh   = (ushort*)(ws + 3010560);     // 50064*128*2 = 12,816,384
    ushort* fl   = (ushort*)(ws + 15827200);    // same size
    float*  sbuf = (float*)(ws + 28643840);     // 25.6 MB fp32
    ushort* tbuf = (ushort*)(ws + 54244096);    // 12.8 MB bf16

    // ---- CSR build ----
    hipMemsetAsync(degi, 0, (size_t)N * sizeof(int), stream);
    count_deg_kernel<<<(NE + 255) / 256, 256, 0, stream>>>(dst, degi, NE);
    block_sums_kernel<<<NB, 256, 0, stream>>>(degi, bsum, N);
    scan_bsums_kernel<<<1, 256, 0, stream>>>(bsum, bbase, NB, offsets, N);
    scatter_offsets_kernel<<<NB, 256, 0, stream>>>(degi, bbase, offsets, cursor, N);
    fill_csr_kernel<<<(NE + 255) / 256, 256, 0, stream>>>(src, dst, cursor, ssrc, NE);

    // ---- weight + feat pre-convert ----
    convert_w_kernel<<<256, 128, 0, stream>>>(ws0, wn0, 128, Bth0, Btl0);
    convert_w_kernel<<<256, 128, 0, stream>>>(ws1, wn1, 128, Bth1, Btl1);
    convert_w_kernel<<<80, 128, 0, stream>>>(ws2, wn2, 40, Bth2, Btl2);
    convert_feat_kernel<<<(N * 128 / 8 + 255) / 256, 256, 0, stream>>>(feat, fh, fl);

    const int gw = (N + RPB - 1) / RPB;  // 521 wide-GEMM blocks (96 rows each)
    const int gn = (N + 63) / 64;        // 782 narrow-GEMM blocks
    const int ga = (N + 3) / 4;          // 12500 agg blocks (4 waves/block)

    // ---- layer 0 ----
    gemm_mfma_wide<<<gw, 512, 0, stream>>>(fh, fl, Bth0, Btl0, b0, sbuf, tbuf, N);
    agg128_split_kernel<<<ga, 256, 0, stream>>>(sbuf, tbuf, offsets, ssrc, fh, fl, N);

    // ---- layer 1 ----
    gemm_mfma_wide<<<gw, 512, 0, stream>>>(fh, fl, Bth1, Btl1, b1, sbuf, tbuf, N);
    agg128_split_kernel<<<ga, 256, 0, stream>>>(sbuf, tbuf, offsets, ssrc, fh, fl, N);

    // ---- layer 2 ----
    gemm_mfma_narrow<<<gn, 256, 0, stream>>>(fh, fl, Bth2, Btl2, b2, sbuf, tbuf, N);
    agg40_kernel<<<ga, 256, 0, stream>>>(sbuf, tbuf, offsets, ssrc, (float*)d_out, N);
}